// Round 9
// baseline (162.322 us; speedup 1.0000x reference)
//
#include <hip/hip_runtime.h>
#include <stdint.h>

#define BATCH 8
#define MPTS 500000
#define NPTS (BATCH * MPTS)            // 4,000,000
#define NBQ 2048                       // 8 batches * (8*4*8) half-buckets of 16x32x16
#define TP 8192                        // points per tile
#define NTILE ((NPTS + TP - 1) / TP)   // 489
#define NIFACE 640                     // interfaces per batch: 224 + 192 + 224
#define NBND (BATCH * NIFACE)          // 5120 boundary blocks
#define FPB 2560                       // face floats per half-bucket

template <int NT>
__device__ __forceinline__ void block_reduce2(float& tv, float& mse) {
    for (int off = 32; off > 0; off >>= 1) {
        tv  += __shfl_down(tv, off, 64);
        mse += __shfl_down(mse, off, 64);
    }
    __shared__ float stv[NT / 64], sms[NT / 64];
    int w = threadIdx.x >> 6, lane = threadIdx.x & 63;
    if (lane == 0) { stv[w] = tv; sms[w] = mse; }
    __syncthreads();
    if (threadIdx.x == 0) {
        float a = 0.f, m = 0.f;
        #pragma unroll
        for (int e = 0; e < NT / 64; ++e) { a += stv[e]; m += sms[e]; }
        tv = a; mse = m;
    }
}

// aux = (q:11 | l:13); half-bucket 16x32x16. aux < 2^24 -> 0xFFFFFFFF safe sentinel.
// q = (b<<8)|(ih<<5)|(jh<<3)|kh ; l = (il<<9)|(jl<<4)|kl
__device__ __forceinline__ uint32_t pack_aux(int b, int i, int j, int k) {
    uint32_t q = ((uint32_t)b << 8) | ((uint32_t)(i >> 4) << 5) |
                 ((uint32_t)(j >> 5) << 3) | (uint32_t)(k >> 4);
    uint32_t l = ((uint32_t)(i & 15) << 9) | ((uint32_t)(j & 31) << 4) | (uint32_t)(k & 15);
    return (q << 13) | l;
}

// LDS bank swizzle: line s = il*32+jl holds 16 dwords; group-of-4 index XORed
// with (s>>1) so wave-wide b128 reads spread across all 32 banks.
__device__ __forceinline__ int gaddr(int s, int kl) {
    return s * 16 + (kl & 3) + ((((kl >> 2) ^ (s >> 1)) & 3) << 2);
}
__device__ __forceinline__ int goff(int s, int c) {
    return ((c ^ (s >> 1)) & 3) << 2;
}

// K1: per-tile bucket histogram (LDS) + packed aux per point, int4-vectorized.
__global__ void __launch_bounds__(1024) hist_k(const int* __restrict__ idx,
                                               uint32_t* __restrict__ hist,
                                               uint32_t* __restrict__ aux) {
    __shared__ uint32_t h[NBQ];
    h[threadIdx.x] = 0; h[threadIdx.x + 1024] = 0;
    __syncthreads();
    int tile = blockIdx.x;
    int p0 = tile * TP;
    int ng = min(TP, NPTS - p0) >> 2;
    for (int g = threadIdx.x; g < ng; g += 1024) {
        int p = p0 + g * 4;
        const int4* ip = (const int4*)(idx + (size_t)p * 3);
        int4 A = ip[0], B = ip[1], C = ip[2];
        int b = p / MPTS;
        uint32_t a0 = pack_aux(b, A.x, A.y, A.z);
        uint32_t a1 = pack_aux(b, A.w, B.x, B.y);
        uint32_t a2 = pack_aux(b, B.z, B.w, C.x);
        uint32_t a3 = pack_aux(b, C.y, C.z, C.w);
        *(uint4*)(aux + p) = make_uint4(a0, a1, a2, a3);
        atomicAdd(&h[a0 >> 13], 1u);
        atomicAdd(&h[a1 >> 13], 1u);
        atomicAdd(&h[a2 >> 13], 1u);
        atomicAdd(&h[a3 >> 13], 1u);
    }
    __syncthreads();
    uint32_t* row = hist + (size_t)tile * NBQ;
    row[threadIdx.x] = h[threadIdx.x];
    row[threadIdx.x + 1024] = h[threadIdx.x + 1024];
}

// K2: per-bucket exclusive scan over tile rows (in place), 16-way batched.
__global__ void __launch_bounds__(64) scan_tiles_k(uint32_t* __restrict__ hist,
                                                   uint32_t* __restrict__ totals) {
    int q = blockIdx.x * 64 + threadIdx.x;   // 32 * 64 = 2048
    uint32_t run = 0;
    for (int t0 = 0; t0 < NTILE; t0 += 16) {
        uint32_t vv[16];
        #pragma unroll
        for (int e = 0; e < 16; ++e) {
            int t = t0 + e;
            vv[e] = (t < NTILE) ? hist[(size_t)t * NBQ + q] : 0u;
        }
        #pragma unroll
        for (int e = 0; e < 16; ++e) {
            int t = t0 + e;
            if (t < NTILE) hist[(size_t)t * NBQ + q] = run;
            run += vv[e];
        }
    }
    totals[q] = run;
}

// K3: exclusive scan of 2048 totals -> base (single block, 256 thr x 8)
__global__ void __launch_bounds__(256) scan_base_k(const uint32_t* __restrict__ totals,
                                                   uint32_t* __restrict__ base) {
    __shared__ uint32_t ssum[256];
    uint32_t loc[8];
    int q0 = threadIdx.x * 8;
    uint32_t s = 0;
    #pragma unroll
    for (int e = 0; e < 8; ++e) { loc[e] = totals[q0 + e]; s += loc[e]; }
    ssum[threadIdx.x] = s;
    __syncthreads();
    for (int off = 1; off < 256; off <<= 1) {
        uint32_t v = 0;
        if (threadIdx.x >= off) v = ssum[threadIdx.x - off];
        __syncthreads();
        if (threadIdx.x >= off) ssum[threadIdx.x] += v;
        __syncthreads();
    }
    uint32_t run = threadIdx.x ? ssum[threadIdx.x - 1] : 0;
    #pragma unroll
    for (int e = 0; e < 8; ++e) { base[q0 + e] = run; run += loc[e]; }
}

// K4: block-local counting sort; aux+val in registers; shuffle block scan over
// 2048 counts (pair per thread); near-coalesced 4B record writeout.
__global__ void __launch_bounds__(1024, 8) reorder_k(const uint32_t* __restrict__ aux,
                                                     const float* __restrict__ val,
                                                     const uint32_t* __restrict__ hist,
                                                     const uint32_t* __restrict__ base,
                                                     uint32_t* __restrict__ rec) {
    __shared__ uint32_t h[NBQ];     // counts -> placement cursors
    __shared__ uint32_t gb[NBQ];    // gb[q] = base[q] + offrow[q] - lstart[q]
    __shared__ uint32_t wtot[16];
    __shared__ uint16_t sq[TP];     // bucket of sorted slot
    __shared__ uint32_t srt[TP];    // sorted packed records
    int tile = blockIdx.x;
    int p0 = tile * TP;
    int cnt = min(TP, NPTS - p0);
    h[threadIdx.x] = 0; h[threadIdx.x + 1024] = 0;
    __syncthreads();
    uint32_t a[8]; float v[8];
    #pragma unroll
    for (int e = 0; e < 8; ++e) {
        int r = threadIdx.x + e * 1024;
        if (r < cnt) {
            a[e] = aux[p0 + r];
            v[e] = val[p0 + r];
            atomicAdd(&h[a[e] >> 13], 1u);
        } else a[e] = 0xFFFFFFFFu;
    }
    __syncthreads();
    // pair-per-thread block exclusive scan of 2048 counts
    int lane = threadIdx.x & 63, wave = threadIdx.x >> 6;
    int q0 = threadIdx.x * 2;
    uint32_t c0 = h[q0], c1 = h[q0 + 1];
    uint32_t ps = c0 + c1;
    uint32_t inc = ps;
    #pragma unroll
    for (int off = 1; off < 64; off <<= 1) {
        uint32_t n = __shfl_up(inc, off, 64);
        if (lane >= off) inc += n;
    }
    if (lane == 63) wtot[wave] = inc;
    __syncthreads();
    if (threadIdx.x < 16) {
        uint32_t w = wtot[threadIdx.x];
        #pragma unroll
        for (int off = 1; off < 16; off <<= 1) {
            uint32_t n = __shfl_up(w, off, 16);
            if ((int)threadIdx.x >= off) w += n;
        }
        wtot[threadIdx.x] = w;
    }
    __syncthreads();
    uint32_t pstart = (wave ? wtot[wave - 1] : 0u) + inc - ps;
    const uint32_t* offrow = hist + (size_t)tile * NBQ;
    gb[q0]     = base[q0]     + offrow[q0]     - pstart;
    gb[q0 + 1] = base[q0 + 1] + offrow[q0 + 1] - (pstart + c0);
    h[q0] = pstart; h[q0 + 1] = pstart + c0;
    __syncthreads();
    #pragma unroll
    for (int e = 0; e < 8; ++e) {
        if (a[e] != 0xFFFFFFFFu) {
            uint32_t qq = a[e] >> 13;
            uint32_t u = (__float_as_uint(v[e]) + 0x1000u) & 0xFFFFE000u;
            uint32_t pos = atomicAdd(&h[qq], 1u);
            srt[pos] = u | (a[e] & 8191u);
            sq[pos]  = (uint16_t)qq;
        }
    }
    __syncthreads();
    for (int t = threadIdx.x; t < cnt; t += 1024)
        rec[gb[sq[t]] + t] = srt[t];
}

// K5: per-half-bucket LDS accumulate (swizzled 32 KB, 16x32x16) + k-line stencil
//     + 6 boundary faces. 512 thr, 4 blocks/CU.
__global__ void __launch_bounds__(512, 8) accum_k(const uint32_t* __restrict__ rec,
                                                  const uint32_t* __restrict__ base,
                                                  const uint32_t* __restrict__ totals,
                                                  float* __restrict__ faces,
                                                  float2* __restrict__ pa) {
    __shared__ float g[8192];   // voxel (s = il*32+jl, kl) at gaddr(s,kl)
    int qb = blockIdx.x;
    {
        float4 z = make_float4(0.f, 0.f, 0.f, 0.f);
        #pragma unroll
        for (int c = 0; c < 4; ++c)
            *(float4*)&g[(threadIdx.x + c * 512) * 4] = z;
    }
    __syncthreads();
    uint32_t s0 = base[qb], cnt = totals[qb];
    for (uint32_t r = threadIdx.x; r < cnt; r += 512) {
        uint32_t e = rec[s0 + r];
        int l = e & 8191;
        atomicAdd(&g[gaddr(l >> 4, l & 15)], __uint_as_float(e & 0xFFFFE000u));
    }
    __syncthreads();
    float tv = 0.f, mse = 0.f;
    {
        int s = threadIdx.x;           // 512 lines, one per thread
        int jl = s & 31, il = s >> 5;
        bool jin = jl < 31, iin = il < 15;
        float own[16];
        #pragma unroll
        for (int c = 0; c < 4; ++c)
            *(float4*)&own[c * 4] = *(const float4*)&g[s * 16 + goff(s, c)];
        #pragma unroll
        for (int k = 0; k < 15; ++k) {
            float d = own[k + 1] - own[k]; tv += fabsf(d); mse += d * d;
        }
        #pragma unroll
        for (int hh = 0; hh < 2; ++hh) {
            if (jin) {
                float jn[8];
                *(float4*)&jn[0] = *(const float4*)&g[(s + 1) * 16 + goff(s + 1, 2 * hh)];
                *(float4*)&jn[4] = *(const float4*)&g[(s + 1) * 16 + goff(s + 1, 2 * hh + 1)];
                #pragma unroll
                for (int k = 0; k < 8; ++k) {
                    float d = jn[k] - own[8 * hh + k]; tv += fabsf(d); mse += d * d;
                }
            }
            if (iin) {
                float inb[8];
                *(float4*)&inb[0] = *(const float4*)&g[(s + 32) * 16 + goff(s + 32, 2 * hh)];
                *(float4*)&inb[4] = *(const float4*)&g[(s + 32) * 16 + goff(s + 32, 2 * hh + 1)];
                #pragma unroll
                for (int k = 0; k < 8; ++k) {
                    float d = inb[k] - own[8 * hh + k]; tv += fabsf(d); mse += d * d;
                }
            }
        }
    }
    // faces: [ i0:512@0 | i15:512@512 | j0:256@1024 | j31:256@1280 | k0:512@1536 | k15:512@2048 ]
    {
        float* f = faces + (size_t)qb * FPB;
        int t = threadIdx.x;
        int hi = t >> 4, lo = t & 15;
        f[t]        = g[gaddr(hi, lo)];              // i=0   (e = jl*16+kl)
        f[512 + t]  = g[gaddr(480 + hi, lo)];        // i=15
        if (t < 256) {
            f[1024 + t] = g[gaddr(hi * 32, lo)];       // j=0  (e = il*16+kl)
            f[1280 + t] = g[gaddr(hi * 32 + 31, lo)];  // j=31
        }
        f[1536 + t] = g[gaddr(t, 0)];                // k=0   (e = il*32+jl = s)
        f[2048 + t] = g[gaddr(t, 15)];               // k=15
    }
    block_reduce2<512>(tv, mse);
    if (threadIdx.x == 0) pa[qb] = make_float2(tv, mse);
}

// K6: cross-half-bucket interface diffs (batch-major partials)
__global__ void __launch_bounds__(256) boundary_k(const float* __restrict__ faces,
                                                  float2* __restrict__ pb) {
    int x = blockIdx.x;
    int b = x / NIFACE;
    int r = x - b * NIFACE;
    int qA, qB, fA, fB, elems;
    if (r < 224) {                      // axis i: 7 x (4 x 8)
        int s = r >> 5, rem = r & 31;
        int u = rem >> 3, w = rem & 7;
        qA = (b << 8) | (s << 5) | (u << 3) | w; qB = qA + 32;
        fA = 512; fB = 0; elems = 512;
    } else if (r < 416) {               // axis j: 3 x (8 x 8)
        int r2 = r - 224;
        int s = r2 >> 6, rem = r2 & 63;
        int u = rem >> 3, w = rem & 7;
        qA = (b << 8) | (u << 5) | (s << 3) | w; qB = qA + 8;
        fA = 1280; fB = 1024; elems = 256;
    } else {                            // axis k: 7 x (8 x 4)
        int r2 = r - 416;
        int s = r2 >> 5, rem = r2 & 31;
        int u = rem >> 2, v = rem & 3;
        qA = (b << 8) | (u << 5) | (v << 3) | s; qB = qA + 1;
        fA = 2048; fB = 1536; elems = 512;
    }
    const float* pA = faces + (size_t)qA * FPB + fA;
    const float* pB = faces + (size_t)qB * FPB + fB;
    float tv = 0.f, mse = 0.f;
    for (int e = threadIdx.x; e < elems; e += 256) {
        float d = pB[e] - pA[e];
        tv += fabsf(d); mse += d * d;
    }
    block_reduce2<256>(tv, mse);
    if (threadIdx.x == 0) pb[x] = make_float2(tv, mse);
}

// K7: final reduction — one block per batch, no atomics
__global__ void __launch_bounds__(256) final_k(const float2* __restrict__ pa,
                                               const float2* __restrict__ pb,
                                               float* __restrict__ out) {
    int b = blockIdx.x;
    float tv = 0.f, mse = 0.f;
    const float2* a = pa + (size_t)b * (NBQ / BATCH);
    for (int i = threadIdx.x; i < NBQ / BATCH; i += 256) { float2 v = a[i]; tv += v.x; mse += v.y; }
    const float2* p = pb + (size_t)b * NIFACE;
    for (int i = threadIdx.x; i < NIFACE; i += 256) { float2 v = p[i]; tv += v.x; mse += v.y; }
    block_reduce2<256>(tv, mse);
    if (threadIdx.x == 0) {
        out[b]     = tv  * (1.f / 2097152.f);   // / X^3
        out[8 + b] = mse * (1.f / 32512.f);     // / (2X^2-2X)
    }
}

extern "C" void kernel_launch(void* const* d_in, const int* in_sizes, int n_in,
                              void* d_out, int out_size, void* d_ws, size_t ws_size,
                              hipStream_t stream) {
    const int*   indices = (const int*)d_in[0];   // (B, M, 3) int32
    const float* values  = (const float*)d_in[1]; // (B, M) float32
    float*       out     = (float*)d_out;         // (2, B) float32

    // workspace (~57 MiB of the 256 MiB pool), no aliasing needed
    uint32_t* hist   = (uint32_t*)d_ws;                       // NTILE*NBQ  (4.0 MB)
    uint32_t* totals = hist + (size_t)NTILE * NBQ;            // NBQ
    uint32_t* base   = totals + NBQ;                          // NBQ
    float2*   pa     = (float2*)(base + NBQ);                 // NBQ        (16 KB)
    float2*   pb     = pa + NBQ;                              // NBND       (40 KB)
    uint32_t* rec    = (uint32_t*)(pb + NBND);                // NPTS       (16 MB)
    uint32_t* aux    = rec + NPTS;                            // NPTS       (16 MB)
    float*    faces  = (float*)(aux + NPTS);                  // NBQ*FPB    (21 MB)

    hist_k      <<<NTILE, 1024, 0, stream>>>(indices, hist, aux);
    scan_tiles_k<<<32,    64,   0, stream>>>(hist, totals);
    scan_base_k <<<1,     256,  0, stream>>>(totals, base);
    reorder_k   <<<NTILE, 1024, 0, stream>>>(aux, values, hist, base, rec);
    accum_k     <<<NBQ,   512,  0, stream>>>(rec, base, totals, faces, pa);
    boundary_k  <<<NBND,  256,  0, stream>>>(faces, pb);
    final_k     <<<BATCH, 256,  0, stream>>>(pa, pb, out);
}

// Round 10
// 147.665 us; speedup vs baseline: 1.0993x; 1.0993x over previous
//
#include <hip/hip_runtime.h>
#include <stdint.h>

#define BATCH 8
#define MPTS 500000
#define NPTS (BATCH * MPTS)            // 4,000,000
#define NBQ 1024                       // 8 batches * (4*4*8) sub-blocks of 32x32x16
#define TP 8192                        // points per tile
#define NTILE ((NPTS + TP - 1) / TP)   // 489
#define HROW (NBQ + 1)                 // offsets row stride (last entry = tile cnt)
#define NIFACE 304                     // interfaces per batch: 96 + 96 + 112
#define NBND (BATCH * NIFACE)          // 2432 boundary blocks

template <int NT>
__device__ __forceinline__ void block_reduce2(float& tv, float& mse) {
    for (int off = 32; off > 0; off >>= 1) {
        tv  += __shfl_down(tv, off, 64);
        mse += __shfl_down(mse, off, 64);
    }
    __shared__ float stv[NT / 64], sms[NT / 64];
    int w = threadIdx.x >> 6, lane = threadIdx.x & 63;
    if (lane == 0) { stv[w] = tv; sms[w] = mse; }
    __syncthreads();
    if (threadIdx.x == 0) {
        float a = 0.f, m = 0.f;
        #pragma unroll
        for (int e = 0; e < NT / 64; ++e) { a += stv[e]; m += sms[e]; }
        tv = a; mse = m;
    }
}

// aux = (q:10 | l:14); sub-block 32x32x16. aux < 2^24 -> 0xFFFFFFFF safe sentinel.
__device__ __forceinline__ uint32_t pack_aux(int b, int i, int j, int k) {
    uint32_t q = ((uint32_t)b << 7) | ((uint32_t)(i >> 5) << 5) |
                 ((uint32_t)(j >> 5) << 3) | (uint32_t)(k >> 4);
    uint32_t l = ((uint32_t)(i & 31) << 9) | ((uint32_t)(j & 31) << 4) | (uint32_t)(k & 15);
    return (q << 14) | l;
}

// LDS bank swizzle: line s = il*32+jl holds 16 dwords; group-of-4 index XORed
// with (s>>1) so wave-wide b128 reads spread across all 32 banks.
__device__ __forceinline__ int gaddr(int s, int kl) {
    return s * 16 + (kl & 3) + ((((kl >> 2) ^ (s >> 1)) & 3) << 2);
}
__device__ __forceinline__ int goff(int s, int c) {
    return ((c ^ (s >> 1)) & 3) << 2;
}

// K1: fused per-tile hist + local exclusive scan + LDS counting sort + coalesced
// writeout into the tile's own slot rec[tile*TP..], plus the offsets row.
// Records are (val_top18 << 14) | local14; value rounded to 18 bits.
__global__ void __launch_bounds__(1024, 8) sort_k(const int* __restrict__ idx,
                                                  const float* __restrict__ val,
                                                  uint32_t* __restrict__ hoff,
                                                  uint32_t* __restrict__ rec) {
    __shared__ uint32_t h[NBQ];     // counts -> placement cursors
    __shared__ uint32_t wtot[16];
    __shared__ uint32_t srt[TP];    // sorted packed records
    int tile = blockIdx.x;
    int p0 = tile * TP;
    int cnt = min(TP, NPTS - p0);   // always a multiple of 4
    h[threadIdx.x] = 0;
    __syncthreads();
    // phase 1: vectorized loads (4 points = 3 int4 + 1 float4), LDS histogram
    uint32_t a[8]; float v[8];
    int ng = cnt >> 2;
    #pragma unroll
    for (int e = 0; e < 2; ++e) {
        int g = threadIdx.x + e * 1024;
        if (g < ng) {
            int p = p0 + g * 4;
            const int4* ip = (const int4*)(idx + (size_t)p * 3);
            int4 A = ip[0], B = ip[1], C = ip[2];
            float4 V = *(const float4*)(val + p);
            int b = p / MPTS;       // groups of 4 never straddle a batch
            a[4*e+0] = pack_aux(b, A.x, A.y, A.z); v[4*e+0] = V.x;
            a[4*e+1] = pack_aux(b, A.w, B.x, B.y); v[4*e+1] = V.y;
            a[4*e+2] = pack_aux(b, B.z, B.w, C.x); v[4*e+2] = V.z;
            a[4*e+3] = pack_aux(b, C.y, C.z, C.w); v[4*e+3] = V.w;
            #pragma unroll
            for (int u = 0; u < 4; ++u) atomicAdd(&h[a[4*e+u] >> 14], 1u);
        } else {
            a[4*e+0] = a[4*e+1] = a[4*e+2] = a[4*e+3] = 0xFFFFFFFFu;
        }
    }
    __syncthreads();
    // phase 2: block exclusive scan of 1024 counts (wave shuffles, 2 barriers)
    int q = threadIdx.x, lane = q & 63, wave = q >> 6;
    uint32_t cq = h[q];
    uint32_t inc = cq;
    #pragma unroll
    for (int off = 1; off < 64; off <<= 1) {
        uint32_t n = __shfl_up(inc, off, 64);
        if (lane >= off) inc += n;
    }
    if (lane == 63) wtot[wave] = inc;
    __syncthreads();
    if (q < 16) {
        uint32_t w = wtot[q];
        #pragma unroll
        for (int off = 1; off < 16; off <<= 1) {
            uint32_t n = __shfl_up(w, off, 16);
            if (q >= off) w += n;
        }
        wtot[q] = w;
    }
    __syncthreads();
    uint32_t lstart = (wave ? wtot[wave - 1] : 0u) + inc - cq;
    hoff[(size_t)tile * HROW + q] = lstart;          // tile-local start offset
    if (q == 0) hoff[(size_t)tile * HROW + NBQ] = (uint32_t)cnt;
    h[q] = lstart;                                    // placement cursor
    __syncthreads();
    // phase 3: place into LDS sorted order
    #pragma unroll
    for (int e = 0; e < 8; ++e) {
        if (a[e] != 0xFFFFFFFFu) {
            uint32_t qq = a[e] >> 14;
            uint32_t u = (__float_as_uint(v[e]) + 0x2000u) & 0xFFFFC000u;
            srt[atomicAdd(&h[qq], 1u)] = u | (a[e] & 16383u);
        }
    }
    __syncthreads();
    // phase 4: fully coalesced linear writeout (uint4)
    uint4* recq = (uint4*)(rec + (size_t)tile * TP);
    const uint4* sr4 = (const uint4*)srt;
    for (int s = threadIdx.x; s < (cnt >> 2); s += 1024) recq[s] = sr4[s];
}

// K2: per-bucket LDS accumulate (swizzled 64 KB). Each thread-pair gathers one
// tile's segment of this bucket (contiguous records), then k-line stencil + faces.
__global__ void __launch_bounds__(1024, 8) accum_k(const uint32_t* __restrict__ rec,
                                                   const uint32_t* __restrict__ hoff,
                                                   float* __restrict__ faces,
                                                   float2* __restrict__ pa) {
    __shared__ float g[16384];   // voxel (s = il*32+jl, kl) at gaddr(s,kl)
    int qb = blockIdx.x;
    {
        float4 z = make_float4(0.f, 0.f, 0.f, 0.f);
        #pragma unroll
        for (int c = 0; c < 4; ++c)
            *(float4*)&g[(threadIdx.x + c * 1024) * 4] = z;
    }
    __syncthreads();
    // segment gather: thread w handles half of tile (w & 511)'s segment
    {
        int t = threadIdx.x & 511, half = threadIdx.x >> 9;
        if (t < NTILE) {
            const uint32_t* row = hoff + (size_t)t * HROW;
            uint32_t s0 = row[qb], s1 = row[qb + 1];
            uint32_t mid = s0 + ((s1 - s0) >> 1);
            uint32_t lo = half ? mid : s0;
            uint32_t hi = half ? s1 : mid;
            const uint32_t* rp = rec + (size_t)t * TP;
            for (uint32_t r = lo; r < hi; ++r) {
                uint32_t e = rp[r];
                int l = e & 16383;
                atomicAdd(&g[gaddr(l >> 4, l & 15)], __uint_as_float(e & 0xFFFFC000u));
            }
        }
    }
    __syncthreads();
    // stencil: thread t owns line s = t (il = t>>5, jl = t&31)
    float tv = 0.f, mse = 0.f;
    {
        int s = threadIdx.x;
        int jl = s & 31, il = s >> 5;
        bool jin = jl < 31, iin = il < 31;
        float own[16];
        #pragma unroll
        for (int c = 0; c < 4; ++c)
            *(float4*)&own[c * 4] = *(const float4*)&g[s * 16 + goff(s, c)];
        #pragma unroll
        for (int k = 0; k < 15; ++k) {
            float d = own[k + 1] - own[k]; tv += fabsf(d); mse += d * d;
        }
        #pragma unroll
        for (int hh = 0; hh < 2; ++hh) {
            if (jin) {
                float jn[8];
                *(float4*)&jn[0] = *(const float4*)&g[(s + 1) * 16 + goff(s + 1, 2 * hh)];
                *(float4*)&jn[4] = *(const float4*)&g[(s + 1) * 16 + goff(s + 1, 2 * hh + 1)];
                #pragma unroll
                for (int k = 0; k < 8; ++k) {
                    float d = jn[k] - own[8 * hh + k]; tv += fabsf(d); mse += d * d;
                }
            }
            if (iin) {
                float inb[8];
                *(float4*)&inb[0] = *(const float4*)&g[(s + 32) * 16 + goff(s + 32, 2 * hh)];
                *(float4*)&inb[4] = *(const float4*)&g[(s + 32) * 16 + goff(s + 32, 2 * hh + 1)];
                #pragma unroll
                for (int k = 0; k < 8; ++k) {
                    float d = inb[k] - own[8 * hh + k]; tv += fabsf(d); mse += d * d;
                }
            }
        }
    }
    // faces: [q][ i0:512 | i31:512 | j0:512 | j31:512 | k0:1024 | k15:1024 ]
    {
        float* f = faces + (size_t)qb * 4096;
        int t = threadIdx.x;
        if (t < 512) {
            int hi = t >> 4, lo = t & 15;
            f[t]        = g[gaddr(hi, lo)];             // i=0  (e = jl*16+kl)
            f[512 + t]  = g[gaddr(992 + hi, lo)];       // i=31
            f[1024 + t] = g[gaddr(hi * 32, lo)];        // j=0  (e = il*16+kl)
            f[1536 + t] = g[gaddr(hi * 32 + 31, lo)];   // j=31
        }
        f[2048 + t] = g[gaddr(t, 0)];                   // k=0  (e = il*32+jl = s)
        f[3072 + t] = g[gaddr(t, 15)];                  // k=15
    }
    block_reduce2<1024>(tv, mse);
    if (threadIdx.x == 0) pa[qb] = make_float2(tv, mse);
}

// K3: cross-sub-block interface diffs from face arrays (batch-major partials)
__global__ void __launch_bounds__(256) boundary_k(const float* __restrict__ faces,
                                                  float2* __restrict__ pb) {
    int x = blockIdx.x;
    int b = x / NIFACE;
    int r = x - b * NIFACE;
    int qA, qB, fA, fB, elems;
    if (r < 96) {                       // axis i
        int s = r >> 5, u = (r >> 3) & 3, w = r & 7;
        qA = (b << 7) | (s << 5) | (u << 3) | w; qB = qA + 32;
        fA = 512; fB = 0; elems = 512;
    } else if (r < 192) {               // axis j
        int r2 = r - 96;
        int s = r2 >> 5, u = (r2 >> 3) & 3, w = r2 & 7;
        qA = (b << 7) | (u << 5) | (s << 3) | w; qB = qA + 8;
        fA = 1536; fB = 1024; elems = 512;
    } else {                            // axis k
        int r2 = r - 192;
        int s = r2 >> 4, u = (r2 >> 2) & 3, v = r2 & 3;
        qA = (b << 7) | (u << 5) | (v << 3) | s; qB = qA + 1;
        fA = 3072; fB = 2048; elems = 1024;
    }
    const float* pA = faces + (size_t)qA * 4096 + fA;
    const float* pB = faces + (size_t)qB * 4096 + fB;
    float tv = 0.f, mse = 0.f;
    for (int e = threadIdx.x; e < elems; e += 256) {
        float d = pB[e] - pA[e];
        tv += fabsf(d); mse += d * d;
    }
    block_reduce2<256>(tv, mse);
    if (threadIdx.x == 0) pb[x] = make_float2(tv, mse);
}

// K4: final reduction — one block per batch, no atomics
__global__ void __launch_bounds__(256) final_k(const float2* __restrict__ pa,
                                               const float2* __restrict__ pb,
                                               float* __restrict__ out) {
    int b = blockIdx.x;
    float tv = 0.f, mse = 0.f;
    const float2* a = pa + (size_t)b * (NBQ / BATCH);
    for (int i = threadIdx.x; i < NBQ / BATCH; i += 256) { float2 v = a[i]; tv += v.x; mse += v.y; }
    const float2* p = pb + (size_t)b * NIFACE;
    for (int i = threadIdx.x; i < NIFACE; i += 256) { float2 v = p[i]; tv += v.x; mse += v.y; }
    block_reduce2<256>(tv, mse);
    if (threadIdx.x == 0) {
        out[b]     = tv  * (1.f / 2097152.f);   // / X^3
        out[8 + b] = mse * (1.f / 32512.f);     // / (2X^2-2X)
    }
}

extern "C" void kernel_launch(void* const* d_in, const int* in_sizes, int n_in,
                              void* d_out, int out_size, void* d_ws, size_t ws_size,
                              hipStream_t stream) {
    const int*   indices = (const int*)d_in[0];   // (B, M, 3) int32
    const float* values  = (const float*)d_in[1]; // (B, M) float32
    float*       out     = (float*)d_out;         // (2, B) float32

    // workspace (~34 MiB)
    uint32_t* hoff  = (uint32_t*)d_ws;                        // NTILE*HROW (2.0 MB)
    float2*   pa    = (float2*)(hoff + (size_t)NTILE * HROW); // NBQ        (8 KB)
    float2*   pb    = pa + NBQ;                               // NBND       (19 KB)
    uint32_t* rec   = (uint32_t*)(pb + NBND);                 // NPTS       (16 MB)
    float*    faces = (float*)(rec + NPTS);                   // NBQ*4096   (16 MB)

    sort_k    <<<NTILE, 1024, 0, stream>>>(indices, values, hoff, rec);
    accum_k   <<<NBQ,   1024, 0, stream>>>(rec, hoff, faces, pa);
    boundary_k<<<NBND,  256,  0, stream>>>(faces, pb);
    final_k   <<<BATCH, 256,  0, stream>>>(pa, pb, out);
}

// Round 11
// 137.344 us; speedup vs baseline: 1.1819x; 1.0751x over previous
//
#include <hip/hip_runtime.h>
#include <stdint.h>

#define BATCH 8
#define MPTS 500000
#define NPTS (BATCH * MPTS)            // 4,000,000
#define NBQ 1024                       // 8 batches * (4*4*8) sub-blocks of 32x32x16
#define TP 8192                        // points per tile
#define NTILE ((NPTS + TP - 1) / TP)   // 489
#define HROW (NBQ + 1)                 // offsets row stride (last entry = tile cnt)
#define NIFACE 304                     // interfaces per batch: 96 + 96 + 112
#define NBND (BATCH * NIFACE)          // 2432 boundary blocks

template <int NT>
__device__ __forceinline__ void block_reduce2(float& tv, float& mse) {
    for (int off = 32; off > 0; off >>= 1) {
        tv  += __shfl_down(tv, off, 64);
        mse += __shfl_down(mse, off, 64);
    }
    __shared__ float stv[NT / 64], sms[NT / 64];
    int w = threadIdx.x >> 6, lane = threadIdx.x & 63;
    if (lane == 0) { stv[w] = tv; sms[w] = mse; }
    __syncthreads();
    if (threadIdx.x == 0) {
        float a = 0.f, m = 0.f;
        #pragma unroll
        for (int e = 0; e < NT / 64; ++e) { a += stv[e]; m += sms[e]; }
        tv = a; mse = m;
    }
}

// aux = (q:10 | l:14); sub-block 32x32x16. aux < 2^24 -> 0xFFFFFFFF safe sentinel.
__device__ __forceinline__ uint32_t pack_aux(int b, int i, int j, int k) {
    uint32_t q = ((uint32_t)b << 7) | ((uint32_t)(i >> 5) << 5) |
                 ((uint32_t)(j >> 5) << 3) | (uint32_t)(k >> 4);
    uint32_t l = ((uint32_t)(i & 31) << 9) | ((uint32_t)(j & 31) << 4) | (uint32_t)(k & 15);
    return (q << 14) | l;
}

// LDS bank swizzle: line s = il*32+jl holds 16 dwords; group-of-4 index XORed
// with (s>>1) so wave-wide b128 reads spread across all 32 banks.
__device__ __forceinline__ int gaddr(int s, int kl) {
    return s * 16 + (kl & 3) + ((((kl >> 2) ^ (s >> 1)) & 3) << 2);
}
__device__ __forceinline__ int goff(int s, int c) {
    return ((c ^ (s >> 1)) & 3) << 2;
}

// K1: fused per-tile hist + local exclusive scan + LDS counting sort + coalesced
// writeout into the tile's own slot rec[tile*TP..], plus the offsets row.
// Records are (val_top18 << 14) | local14; value rounded to 18 bits.
__global__ void __launch_bounds__(1024, 8) sort_k(const int* __restrict__ idx,
                                                  const float* __restrict__ val,
                                                  uint32_t* __restrict__ hoff,
                                                  uint32_t* __restrict__ rec) {
    __shared__ uint32_t h[NBQ];     // counts -> placement cursors
    __shared__ uint32_t wtot[16];
    __shared__ uint32_t srt[TP];    // sorted packed records
    int tile = blockIdx.x;
    int p0 = tile * TP;
    int cnt = min(TP, NPTS - p0);   // always a multiple of 4
    h[threadIdx.x] = 0;
    __syncthreads();
    // phase 1: vectorized loads (4 points = 3 int4 + 1 float4), LDS histogram
    uint32_t a[8]; float v[8];
    int ng = cnt >> 2;
    #pragma unroll
    for (int e = 0; e < 2; ++e) {
        int g = threadIdx.x + e * 1024;
        if (g < ng) {
            int p = p0 + g * 4;
            const int4* ip = (const int4*)(idx + (size_t)p * 3);
            int4 A = ip[0], B = ip[1], C = ip[2];
            float4 V = *(const float4*)(val + p);
            int b = p / MPTS;       // groups of 4 never straddle a batch
            a[4*e+0] = pack_aux(b, A.x, A.y, A.z); v[4*e+0] = V.x;
            a[4*e+1] = pack_aux(b, A.w, B.x, B.y); v[4*e+1] = V.y;
            a[4*e+2] = pack_aux(b, B.z, B.w, C.x); v[4*e+2] = V.z;
            a[4*e+3] = pack_aux(b, C.y, C.z, C.w); v[4*e+3] = V.w;
            #pragma unroll
            for (int u = 0; u < 4; ++u) atomicAdd(&h[a[4*e+u] >> 14], 1u);
        } else {
            a[4*e+0] = a[4*e+1] = a[4*e+2] = a[4*e+3] = 0xFFFFFFFFu;
        }
    }
    __syncthreads();
    // phase 2: block exclusive scan of 1024 counts (wave shuffles, 2 barriers)
    int q = threadIdx.x, lane = q & 63, wave = q >> 6;
    uint32_t cq = h[q];
    uint32_t inc = cq;
    #pragma unroll
    for (int off = 1; off < 64; off <<= 1) {
        uint32_t n = __shfl_up(inc, off, 64);
        if (lane >= off) inc += n;
    }
    if (lane == 63) wtot[wave] = inc;
    __syncthreads();
    if (q < 16) {
        uint32_t w = wtot[q];
        #pragma unroll
        for (int off = 1; off < 16; off <<= 1) {
            uint32_t n = __shfl_up(w, off, 16);
            if (q >= off) w += n;
        }
        wtot[q] = w;
    }
    __syncthreads();
    uint32_t lstart = (wave ? wtot[wave - 1] : 0u) + inc - cq;
    hoff[(size_t)tile * HROW + q] = lstart;          // tile-local start offset
    if (q == 0) hoff[(size_t)tile * HROW + NBQ] = (uint32_t)cnt;
    h[q] = lstart;                                    // placement cursor
    __syncthreads();
    // phase 3: place into LDS sorted order
    #pragma unroll
    for (int e = 0; e < 8; ++e) {
        if (a[e] != 0xFFFFFFFFu) {
            uint32_t qq = a[e] >> 14;
            uint32_t u = (__float_as_uint(v[e]) + 0x2000u) & 0xFFFFC000u;
            srt[atomicAdd(&h[qq], 1u)] = u | (a[e] & 16383u);
        }
    }
    __syncthreads();
    // phase 4: fully coalesced linear writeout (uint4)
    uint4* recq = (uint4*)(rec + (size_t)tile * TP);
    const uint4* sr4 = (const uint4*)srt;
    for (int s = threadIdx.x; s < (cnt >> 2); s += 1024) recq[s] = sr4[s];
}

// K2: per-bucket LDS accumulate (swizzled 64 KB). Gather is 8-lanes-per-tile:
// a wave touches 8 short contiguous segment spans per load op (coalesced within
// span, row offsets broadcast within each 8-lane group). Then stencil + faces.
__global__ void __launch_bounds__(1024, 8) accum_k(const uint32_t* __restrict__ rec,
                                                   const uint32_t* __restrict__ hoff,
                                                   float* __restrict__ faces,
                                                   float2* __restrict__ pa) {
    __shared__ float g[16384];   // voxel (s = il*32+jl, kl) at gaddr(s,kl)
    int qb = blockIdx.x;
    {
        float4 z = make_float4(0.f, 0.f, 0.f, 0.f);
        #pragma unroll
        for (int c = 0; c < 4; ++c)
            *(float4*)&g[(threadIdx.x + c * 1024) * 4] = z;
    }
    __syncthreads();
    // segment gather: 8-lane group grp handles tiles grp, grp+128, ...
    {
        int grp = threadIdx.x >> 3;      // 0..127
        int r8  = threadIdx.x & 7;
        for (int t = grp; t < NTILE; t += 128) {
            const uint32_t* row = hoff + (size_t)t * HROW;
            uint32_t s0 = row[qb], s1 = row[qb + 1];   // broadcast within group
            const uint32_t* rp = rec + (size_t)t * TP;
            for (uint32_t r = s0 + r8; r < s1; r += 8) {
                uint32_t e = rp[r];
                int l = e & 16383;
                atomicAdd(&g[gaddr(l >> 4, l & 15)], __uint_as_float(e & 0xFFFFC000u));
            }
        }
    }
    __syncthreads();
    // stencil: thread t owns line s = t (il = t>>5, jl = t&31)
    float tv = 0.f, mse = 0.f;
    {
        int s = threadIdx.x;
        int jl = s & 31, il = s >> 5;
        bool jin = jl < 31, iin = il < 31;
        float own[16];
        #pragma unroll
        for (int c = 0; c < 4; ++c)
            *(float4*)&own[c * 4] = *(const float4*)&g[s * 16 + goff(s, c)];
        #pragma unroll
        for (int k = 0; k < 15; ++k) {
            float d = own[k + 1] - own[k]; tv += fabsf(d); mse += d * d;
        }
        #pragma unroll
        for (int hh = 0; hh < 2; ++hh) {
            if (jin) {
                float jn[8];
                *(float4*)&jn[0] = *(const float4*)&g[(s + 1) * 16 + goff(s + 1, 2 * hh)];
                *(float4*)&jn[4] = *(const float4*)&g[(s + 1) * 16 + goff(s + 1, 2 * hh + 1)];
                #pragma unroll
                for (int k = 0; k < 8; ++k) {
                    float d = jn[k] - own[8 * hh + k]; tv += fabsf(d); mse += d * d;
                }
            }
            if (iin) {
                float inb[8];
                *(float4*)&inb[0] = *(const float4*)&g[(s + 32) * 16 + goff(s + 32, 2 * hh)];
                *(float4*)&inb[4] = *(const float4*)&g[(s + 32) * 16 + goff(s + 32, 2 * hh + 1)];
                #pragma unroll
                for (int k = 0; k < 8; ++k) {
                    float d = inb[k] - own[8 * hh + k]; tv += fabsf(d); mse += d * d;
                }
            }
        }
    }
    // faces: [q][ i0:512 | i31:512 | j0:512 | j31:512 | k0:1024 | k15:1024 ]
    {
        float* f = faces + (size_t)qb * 4096;
        int t = threadIdx.x;
        if (t < 512) {
            int hi = t >> 4, lo = t & 15;
            f[t]        = g[gaddr(hi, lo)];             // i=0  (e = jl*16+kl)
            f[512 + t]  = g[gaddr(992 + hi, lo)];       // i=31
            f[1024 + t] = g[gaddr(hi * 32, lo)];        // j=0  (e = il*16+kl)
            f[1536 + t] = g[gaddr(hi * 32 + 31, lo)];   // j=31
        }
        f[2048 + t] = g[gaddr(t, 0)];                   // k=0  (e = il*32+jl = s)
        f[3072 + t] = g[gaddr(t, 15)];                  // k=15
    }
    block_reduce2<1024>(tv, mse);
    if (threadIdx.x == 0) pa[qb] = make_float2(tv, mse);
}

// K3: cross-sub-block interface diffs from face arrays (batch-major partials)
__global__ void __launch_bounds__(256) boundary_k(const float* __restrict__ faces,
                                                  float2* __restrict__ pb) {
    int x = blockIdx.x;
    int b = x / NIFACE;
    int r = x - b * NIFACE;
    int qA, qB, fA, fB, elems;
    if (r < 96) {                       // axis i
        int s = r >> 5, u = (r >> 3) & 3, w = r & 7;
        qA = (b << 7) | (s << 5) | (u << 3) | w; qB = qA + 32;
        fA = 512; fB = 0; elems = 512;
    } else if (r < 192) {               // axis j
        int r2 = r - 96;
        int s = r2 >> 5, u = (r2 >> 3) & 3, w = r2 & 7;
        qA = (b << 7) | (u << 5) | (s << 3) | w; qB = qA + 8;
        fA = 1536; fB = 1024; elems = 512;
    } else {                            // axis k
        int r2 = r - 192;
        int s = r2 >> 4, u = (r2 >> 2) & 3, v = r2 & 3;
        qA = (b << 7) | (u << 5) | (v << 3) | s; qB = qA + 1;
        fA = 3072; fB = 2048; elems = 1024;
    }
    const float* pA = faces + (size_t)qA * 4096 + fA;
    const float* pB = faces + (size_t)qB * 4096 + fB;
    float tv = 0.f, mse = 0.f;
    for (int e = threadIdx.x; e < elems; e += 256) {
        float d = pB[e] - pA[e];
        tv += fabsf(d); mse += d * d;
    }
    block_reduce2<256>(tv, mse);
    if (threadIdx.x == 0) pb[x] = make_float2(tv, mse);
}

// K4: final reduction — one block per batch, no atomics
__global__ void __launch_bounds__(256) final_k(const float2* __restrict__ pa,
                                               const float2* __restrict__ pb,
                                               float* __restrict__ out) {
    int b = blockIdx.x;
    float tv = 0.f, mse = 0.f;
    const float2* a = pa + (size_t)b * (NBQ / BATCH);
    for (int i = threadIdx.x; i < NBQ / BATCH; i += 256) { float2 v = a[i]; tv += v.x; mse += v.y; }
    const float2* p = pb + (size_t)b * NIFACE;
    for (int i = threadIdx.x; i < NIFACE; i += 256) { float2 v = p[i]; tv += v.x; mse += v.y; }
    block_reduce2<256>(tv, mse);
    if (threadIdx.x == 0) {
        out[b]     = tv  * (1.f / 2097152.f);   // / X^3
        out[8 + b] = mse * (1.f / 32512.f);     // / (2X^2-2X)
    }
}

extern "C" void kernel_launch(void* const* d_in, const int* in_sizes, int n_in,
                              void* d_out, int out_size, void* d_ws, size_t ws_size,
                              hipStream_t stream) {
    const int*   indices = (const int*)d_in[0];   // (B, M, 3) int32
    const float* values  = (const float*)d_in[1]; // (B, M) float32
    float*       out     = (float*)d_out;         // (2, B) float32

    // workspace (~34 MiB)
    uint32_t* hoff  = (uint32_t*)d_ws;                        // NTILE*HROW (2.0 MB)
    float2*   pa    = (float2*)(hoff + (size_t)NTILE * HROW); // NBQ        (8 KB)
    float2*   pb    = pa + NBQ;                               // NBND       (19 KB)
    uint32_t* rec   = (uint32_t*)(pb + NBND);                 // NPTS       (16 MB)
    float*    faces = (float*)(rec + NPTS);                   // NBQ*4096   (16 MB)

    sort_k    <<<NTILE, 1024, 0, stream>>>(indices, values, hoff, rec);
    accum_k   <<<NBQ,   1024, 0, stream>>>(rec, hoff, faces, pa);
    boundary_k<<<NBND,  256,  0, stream>>>(faces, pb);
    final_k   <<<BATCH, 256,  0, stream>>>(pa, pb, out);
}

// Round 12
// 136.600 us; speedup vs baseline: 1.1883x; 1.0054x over previous
//
#include <hip/hip_runtime.h>
#include <stdint.h>

#define BATCH 8
#define MPTS 500000
#define NPTS (BATCH * MPTS)            // 4,000,000
#define NBQ 1024                       // 8 batches * (4*4*8) sub-blocks of 32x32x16
#define TP 8192                        // points per tile
#define NTILE ((NPTS + TP - 1) / TP)   // 489
#define HROW (NBQ + 1)                 // offsets row stride (last entry = tile cnt)
#define NIFACE 304                     // interfaces per batch: 96 + 96 + 112
#define NBND (BATCH * NIFACE)          // 2432 boundary blocks

template <int NT>
__device__ __forceinline__ void block_reduce2(float& tv, float& mse) {
    for (int off = 32; off > 0; off >>= 1) {
        tv  += __shfl_down(tv, off, 64);
        mse += __shfl_down(mse, off, 64);
    }
    __shared__ float stv[NT / 64], sms[NT / 64];
    int w = threadIdx.x >> 6, lane = threadIdx.x & 63;
    if (lane == 0) { stv[w] = tv; sms[w] = mse; }
    __syncthreads();
    if (threadIdx.x == 0) {
        float a = 0.f, m = 0.f;
        #pragma unroll
        for (int e = 0; e < NT / 64; ++e) { a += stv[e]; m += sms[e]; }
        tv = a; mse = m;
    }
}

// aux = (q:10 | l:14); sub-block 32x32x16. aux < 2^24 -> 0xFFFFFFFF safe sentinel.
__device__ __forceinline__ uint32_t pack_aux(int b, int i, int j, int k) {
    uint32_t q = ((uint32_t)b << 7) | ((uint32_t)(i >> 5) << 5) |
                 ((uint32_t)(j >> 5) << 3) | (uint32_t)(k >> 4);
    uint32_t l = ((uint32_t)(i & 31) << 9) | ((uint32_t)(j & 31) << 4) | (uint32_t)(k & 15);
    return (q << 14) | l;
}

// LDS bank swizzle: line s = il*32+jl holds 16 dwords; group-of-4 index XORed
// with (s>>1) so wave-wide b128 reads spread across all 32 banks.
__device__ __forceinline__ int gaddr(int s, int kl) {
    return s * 16 + (kl & 3) + ((((kl >> 2) ^ (s >> 1)) & 3) << 2);
}
__device__ __forceinline__ int goff(int s, int c) {
    return ((c ^ (s >> 1)) & 3) << 2;
}

// K1: fused per-tile hist + local exclusive scan + LDS counting sort + coalesced
// writeout into the tile's own slot rec[tile*TP..], plus the offsets row.
// Records are (val_top18 << 14) | local14; value rounded to 18 bits.
__global__ void __launch_bounds__(1024, 8) sort_k(const int* __restrict__ idx,
                                                  const float* __restrict__ val,
                                                  uint32_t* __restrict__ hoff,
                                                  uint32_t* __restrict__ rec) {
    __shared__ uint32_t h[NBQ];     // counts -> placement cursors
    __shared__ uint32_t wtot[16];
    __shared__ uint32_t srt[TP];    // sorted packed records
    int tile = blockIdx.x;
    int p0 = tile * TP;
    int cnt = min(TP, NPTS - p0);   // always a multiple of 4
    h[threadIdx.x] = 0;
    __syncthreads();
    // phase 1: vectorized loads (4 points = 3 int4 + 1 float4), LDS histogram
    uint32_t a[8]; float v[8];
    int ng = cnt >> 2;
    #pragma unroll
    for (int e = 0; e < 2; ++e) {
        int g = threadIdx.x + e * 1024;
        if (g < ng) {
            int p = p0 + g * 4;
            const int4* ip = (const int4*)(idx + (size_t)p * 3);
            int4 A = ip[0], B = ip[1], C = ip[2];
            float4 V = *(const float4*)(val + p);
            int b = p / MPTS;       // groups of 4 never straddle a batch
            a[4*e+0] = pack_aux(b, A.x, A.y, A.z); v[4*e+0] = V.x;
            a[4*e+1] = pack_aux(b, A.w, B.x, B.y); v[4*e+1] = V.y;
            a[4*e+2] = pack_aux(b, B.z, B.w, C.x); v[4*e+2] = V.z;
            a[4*e+3] = pack_aux(b, C.y, C.z, C.w); v[4*e+3] = V.w;
            #pragma unroll
            for (int u = 0; u < 4; ++u) atomicAdd(&h[a[4*e+u] >> 14], 1u);
        } else {
            a[4*e+0] = a[4*e+1] = a[4*e+2] = a[4*e+3] = 0xFFFFFFFFu;
        }
    }
    __syncthreads();
    // phase 2: block exclusive scan of 1024 counts (wave shuffles, 2 barriers)
    int q = threadIdx.x, lane = q & 63, wave = q >> 6;
    uint32_t cq = h[q];
    uint32_t inc = cq;
    #pragma unroll
    for (int off = 1; off < 64; off <<= 1) {
        uint32_t n = __shfl_up(inc, off, 64);
        if (lane >= off) inc += n;
    }
    if (lane == 63) wtot[wave] = inc;
    __syncthreads();
    if (q < 16) {
        uint32_t w = wtot[q];
        #pragma unroll
        for (int off = 1; off < 16; off <<= 1) {
            uint32_t n = __shfl_up(w, off, 16);
            if (q >= off) w += n;
        }
        wtot[q] = w;
    }
    __syncthreads();
    uint32_t lstart = (wave ? wtot[wave - 1] : 0u) + inc - cq;
    hoff[(size_t)tile * HROW + q] = lstart;          // tile-local start offset
    if (q == 0) hoff[(size_t)tile * HROW + NBQ] = (uint32_t)cnt;
    h[q] = lstart;                                    // placement cursor
    __syncthreads();
    // phase 3: place into LDS sorted order
    #pragma unroll
    for (int e = 0; e < 8; ++e) {
        if (a[e] != 0xFFFFFFFFu) {
            uint32_t qq = a[e] >> 14;
            uint32_t u = (__float_as_uint(v[e]) + 0x2000u) & 0xFFFFC000u;
            srt[atomicAdd(&h[qq], 1u)] = u | (a[e] & 16383u);
        }
    }
    __syncthreads();
    // phase 4: fully coalesced linear writeout (uint4)
    uint4* recq = (uint4*)(rec + (size_t)tile * TP);
    const uint4* sr4 = (const uint4*)srt;
    for (int s = threadIdx.x; s < (cnt >> 2); s += 1024) recq[s] = sr4[s];
}

// K2: per-bucket LDS accumulate (swizzled 64 KB). Gather is 8-lanes-per-tile.
// XCD-aware bucket swizzle: consecutive buckets (which share rec cache lines,
// ~8 records/bucket per tile) are processed by blocks on the SAME XCD so the
// shared lines stay in one per-XCD L2 instead of ping-ponging across 4.
__global__ void __launch_bounds__(1024, 8) accum_k(const uint32_t* __restrict__ rec,
                                                   const uint32_t* __restrict__ hoff,
                                                   float* __restrict__ faces,
                                                   float2* __restrict__ pa) {
    __shared__ float g[16384];   // voxel (s = il*32+jl, kl) at gaddr(s,kl)
    int b = blockIdx.x;
    int qb = ((b & 7) << 7) | (b >> 3);   // XCD x (~ b%8) gets buckets [128x, 128x+128)
    {
        float4 z = make_float4(0.f, 0.f, 0.f, 0.f);
        #pragma unroll
        for (int c = 0; c < 4; ++c)
            *(float4*)&g[(threadIdx.x + c * 1024) * 4] = z;
    }
    __syncthreads();
    // segment gather: 8-lane group grp handles tiles grp, grp+128, ... (unroll 2)
    {
        int grp = threadIdx.x >> 3;      // 0..127
        int r8  = threadIdx.x & 7;
        for (int t = grp; t < NTILE; t += 256) {
            const uint32_t* rowA = hoff + (size_t)t * HROW;
            uint32_t a0 = rowA[qb], a1 = rowA[qb + 1];
            const uint32_t* rpA = rec + (size_t)t * TP;
            uint32_t b0 = 0, b1 = 0;
            const uint32_t* rpB = nullptr;
            if (t + 128 < NTILE) {
                const uint32_t* rowB = hoff + (size_t)(t + 128) * HROW;
                b0 = rowB[qb]; b1 = rowB[qb + 1];
                rpB = rec + (size_t)(t + 128) * TP;
            }
            for (uint32_t r = a0 + r8; r < a1; r += 8) {
                uint32_t e = rpA[r];
                int l = e & 16383;
                atomicAdd(&g[gaddr(l >> 4, l & 15)], __uint_as_float(e & 0xFFFFC000u));
            }
            if (rpB) {
                for (uint32_t r = b0 + r8; r < b1; r += 8) {
                    uint32_t e = rpB[r];
                    int l = e & 16383;
                    atomicAdd(&g[gaddr(l >> 4, l & 15)], __uint_as_float(e & 0xFFFFC000u));
                }
            }
        }
    }
    __syncthreads();
    // stencil: thread t owns line s = t (il = t>>5, jl = t&31)
    float tv = 0.f, mse = 0.f;
    {
        int s = threadIdx.x;
        int jl = s & 31, il = s >> 5;
        bool jin = jl < 31, iin = il < 31;
        float own[16];
        #pragma unroll
        for (int c = 0; c < 4; ++c)
            *(float4*)&own[c * 4] = *(const float4*)&g[s * 16 + goff(s, c)];
        #pragma unroll
        for (int k = 0; k < 15; ++k) {
            float d = own[k + 1] - own[k]; tv += fabsf(d); mse += d * d;
        }
        #pragma unroll
        for (int hh = 0; hh < 2; ++hh) {
            if (jin) {
                float jn[8];
                *(float4*)&jn[0] = *(const float4*)&g[(s + 1) * 16 + goff(s + 1, 2 * hh)];
                *(float4*)&jn[4] = *(const float4*)&g[(s + 1) * 16 + goff(s + 1, 2 * hh + 1)];
                #pragma unroll
                for (int k = 0; k < 8; ++k) {
                    float d = jn[k] - own[8 * hh + k]; tv += fabsf(d); mse += d * d;
                }
            }
            if (iin) {
                float inb[8];
                *(float4*)&inb[0] = *(const float4*)&g[(s + 32) * 16 + goff(s + 32, 2 * hh)];
                *(float4*)&inb[4] = *(const float4*)&g[(s + 32) * 16 + goff(s + 32, 2 * hh + 1)];
                #pragma unroll
                for (int k = 0; k < 8; ++k) {
                    float d = inb[k] - own[8 * hh + k]; tv += fabsf(d); mse += d * d;
                }
            }
        }
    }
    // faces: [q][ i0:512 | i31:512 | j0:512 | j31:512 | k0:1024 | k15:1024 ]
    {
        float* f = faces + (size_t)qb * 4096;
        int t = threadIdx.x;
        if (t < 512) {
            int hi = t >> 4, lo = t & 15;
            f[t]        = g[gaddr(hi, lo)];             // i=0  (e = jl*16+kl)
            f[512 + t]  = g[gaddr(992 + hi, lo)];       // i=31
            f[1024 + t] = g[gaddr(hi * 32, lo)];        // j=0  (e = il*16+kl)
            f[1536 + t] = g[gaddr(hi * 32 + 31, lo)];   // j=31
        }
        f[2048 + t] = g[gaddr(t, 0)];                   // k=0  (e = il*32+jl = s)
        f[3072 + t] = g[gaddr(t, 15)];                  // k=15
    }
    block_reduce2<1024>(tv, mse);
    if (threadIdx.x == 0) pa[qb] = make_float2(tv, mse);
}

// K3: cross-sub-block interface diffs from face arrays (batch-major partials)
__global__ void __launch_bounds__(256) boundary_k(const float* __restrict__ faces,
                                                  float2* __restrict__ pb) {
    int x = blockIdx.x;
    int b = x / NIFACE;
    int r = x - b * NIFACE;
    int qA, qB, fA, fB, elems;
    if (r < 96) {                       // axis i
        int s = r >> 5, u = (r >> 3) & 3, w = r & 7;
        qA = (b << 7) | (s << 5) | (u << 3) | w; qB = qA + 32;
        fA = 512; fB = 0; elems = 512;
    } else if (r < 192) {               // axis j
        int r2 = r - 96;
        int s = r2 >> 5, u = (r2 >> 3) & 3, w = r2 & 7;
        qA = (b << 7) | (u << 5) | (s << 3) | w; qB = qA + 8;
        fA = 1536; fB = 1024; elems = 512;
    } else {                            // axis k
        int r2 = r - 192;
        int s = r2 >> 4, u = (r2 >> 2) & 3, v = r2 & 3;
        qA = (b << 7) | (u << 5) | (v << 3) | s; qB = qA + 1;
        fA = 3072; fB = 2048; elems = 1024;
    }
    const float* pA = faces + (size_t)qA * 4096 + fA;
    const float* pB = faces + (size_t)qB * 4096 + fB;
    float tv = 0.f, mse = 0.f;
    for (int e = threadIdx.x; e < elems; e += 256) {
        float d = pB[e] - pA[e];
        tv += fabsf(d); mse += d * d;
    }
    block_reduce2<256>(tv, mse);
    if (threadIdx.x == 0) pb[x] = make_float2(tv, mse);
}

// K4: final reduction — one block per batch, no atomics
__global__ void __launch_bounds__(256) final_k(const float2* __restrict__ pa,
                                               const float2* __restrict__ pb,
                                               float* __restrict__ out) {
    int b = blockIdx.x;
    float tv = 0.f, mse = 0.f;
    const float2* a = pa + (size_t)b * (NBQ / BATCH);
    for (int i = threadIdx.x; i < NBQ / BATCH; i += 256) { float2 v = a[i]; tv += v.x; mse += v.y; }
    const float2* p = pb + (size_t)b * NIFACE;
    for (int i = threadIdx.x; i < NIFACE; i += 256) { float2 v = p[i]; tv += v.x; mse += v.y; }
    block_reduce2<256>(tv, mse);
    if (threadIdx.x == 0) {
        out[b]     = tv  * (1.f / 2097152.f);   // / X^3
        out[8 + b] = mse * (1.f / 32512.f);     // / (2X^2-2X)
    }
}

extern "C" void kernel_launch(void* const* d_in, const int* in_sizes, int n_in,
                              void* d_out, int out_size, void* d_ws, size_t ws_size,
                              hipStream_t stream) {
    const int*   indices = (const int*)d_in[0];   // (B, M, 3) int32
    const float* values  = (const float*)d_in[1]; // (B, M) float32
    float*       out     = (float*)d_out;         // (2, B) float32

    // workspace (~34 MiB)
    uint32_t* hoff  = (uint32_t*)d_ws;                        // NTILE*HROW (2.0 MB)
    float2*   pa    = (float2*)(hoff + (size_t)NTILE * HROW); // NBQ        (8 KB)
    float2*   pb    = pa + NBQ;                               // NBND       (19 KB)
    uint32_t* rec   = (uint32_t*)(pb + NBND);                 // NPTS       (16 MB)
    float*    faces = (float*)(rec + NPTS);                   // NBQ*4096   (16 MB)

    sort_k    <<<NTILE, 1024, 0, stream>>>(indices, values, hoff, rec);
    accum_k   <<<NBQ,   1024, 0, stream>>>(rec, hoff, faces, pa);
    boundary_k<<<NBND,  256,  0, stream>>>(faces, pb);
    final_k   <<<BATCH, 256,  0, stream>>>(pa, pb, out);
}

// Round 13
// 136.197 us; speedup vs baseline: 1.1918x; 1.0030x over previous
//
#include <hip/hip_runtime.h>
#include <stdint.h>

#define BATCH 8
#define MPTS 500000
#define NPTS (BATCH * MPTS)            // 4,000,000
#define NBQ 1024                       // 8 batches * (4*4*8) sub-blocks of 32x32x16
#define TP 16384                       // points per tile
#define NTILE ((NPTS + TP - 1) / TP)   // 245
#define HROW (NBQ + 1)                 // offsets row stride (last entry = tile cnt)
#define NIFACE 304                     // interfaces per batch: 96 + 96 + 112
#define NBND (BATCH * NIFACE)          // 2432 boundary blocks

template <int NT>
__device__ __forceinline__ void block_reduce2(float& tv, float& mse) {
    for (int off = 32; off > 0; off >>= 1) {
        tv  += __shfl_down(tv, off, 64);
        mse += __shfl_down(mse, off, 64);
    }
    __shared__ float stv[NT / 64], sms[NT / 64];
    int w = threadIdx.x >> 6, lane = threadIdx.x & 63;
    if (lane == 0) { stv[w] = tv; sms[w] = mse; }
    __syncthreads();
    if (threadIdx.x == 0) {
        float a = 0.f, m = 0.f;
        #pragma unroll
        for (int e = 0; e < NT / 64; ++e) { a += stv[e]; m += sms[e]; }
        tv = a; mse = m;
    }
}

// aux = (q:10 | l:14); sub-block 32x32x16. aux < 2^24 -> 0xFFFFFFFF safe sentinel.
__device__ __forceinline__ uint32_t pack_aux(int b, int i, int j, int k) {
    uint32_t q = ((uint32_t)b << 7) | ((uint32_t)(i >> 5) << 5) |
                 ((uint32_t)(j >> 5) << 3) | (uint32_t)(k >> 4);
    uint32_t l = ((uint32_t)(i & 31) << 9) | ((uint32_t)(j & 31) << 4) | (uint32_t)(k & 15);
    return (q << 14) | l;
}

// LDS bank swizzle: line s = il*32+jl holds 16 dwords; group-of-4 index XORed
// with (s>>1) so wave-wide b128 reads spread across all 32 banks.
__device__ __forceinline__ int gaddr(int s, int kl) {
    return s * 16 + (kl & 3) + ((((kl >> 2) ^ (s >> 1)) & 3) << 2);
}
__device__ __forceinline__ int goff(int s, int c) {
    return ((c ^ (s >> 1)) & 3) << 2;
}

// round float bits to top-16 (sign+exp+7man), round-half-up
__device__ __forceinline__ uint32_t val16(float f) {
    return (__float_as_uint(f) + 0x8000u) >> 16;
}

// K1: fused per-tile hist + local exclusive scan + LDS counting sort + coalesced
// writeout. Record = (val16 << 16) | local14 (bits 14-15 zero).
__global__ void __launch_bounds__(1024, 8) sort_k(const int* __restrict__ idx,
                                                  const float* __restrict__ val,
                                                  uint32_t* __restrict__ hoff,
                                                  uint32_t* __restrict__ rec) {
    __shared__ uint32_t h[NBQ];     // counts -> placement cursors
    __shared__ uint32_t wtot[16];
    __shared__ uint32_t srt[TP];    // sorted packed records (64 KB)
    int tile = blockIdx.x;
    int p0 = tile * TP;
    int cnt = min(TP, NPTS - p0);   // always a multiple of 4
    h[threadIdx.x] = 0;
    __syncthreads();
    // phase 1: vectorized loads (4 points = 3 int4 + 1 float4), LDS histogram.
    // Hold 16 aux (24-bit) + 16 vals packed 16-bit into vpk[8].
    uint32_t a[16]; uint32_t vpk[8];
    int ng = cnt >> 2;
    #pragma unroll
    for (int e = 0; e < 4; ++e) {
        int g = threadIdx.x + e * 1024;
        if (g < ng) {
            int p = p0 + g * 4;
            const int4* ip = (const int4*)(idx + (size_t)p * 3);
            int4 A = ip[0], B = ip[1], C = ip[2];
            float4 V = *(const float4*)(val + p);
            int b = p / MPTS;       // groups of 4 never straddle a batch
            a[4*e+0] = pack_aux(b, A.x, A.y, A.z);
            a[4*e+1] = pack_aux(b, A.w, B.x, B.y);
            a[4*e+2] = pack_aux(b, B.z, B.w, C.x);
            a[4*e+3] = pack_aux(b, C.y, C.z, C.w);
            vpk[2*e]     = val16(V.x) | (val16(V.y) << 16);
            vpk[2*e + 1] = val16(V.z) | (val16(V.w) << 16);
            #pragma unroll
            for (int u = 0; u < 4; ++u) atomicAdd(&h[a[4*e+u] >> 14], 1u);
        } else {
            a[4*e+0] = a[4*e+1] = a[4*e+2] = a[4*e+3] = 0xFFFFFFFFu;
            vpk[2*e] = vpk[2*e + 1] = 0u;
        }
    }
    __syncthreads();
    // phase 2: block exclusive scan of 1024 counts (wave shuffles, 2 barriers)
    int q = threadIdx.x, lane = q & 63, wave = q >> 6;
    uint32_t cq = h[q];
    uint32_t inc = cq;
    #pragma unroll
    for (int off = 1; off < 64; off <<= 1) {
        uint32_t n = __shfl_up(inc, off, 64);
        if (lane >= off) inc += n;
    }
    if (lane == 63) wtot[wave] = inc;
    __syncthreads();
    if (q < 16) {
        uint32_t w = wtot[q];
        #pragma unroll
        for (int off = 1; off < 16; off <<= 1) {
            uint32_t n = __shfl_up(w, off, 16);
            if (q >= off) w += n;
        }
        wtot[q] = w;
    }
    __syncthreads();
    uint32_t lstart = (wave ? wtot[wave - 1] : 0u) + inc - cq;
    hoff[(size_t)tile * HROW + q] = lstart;          // tile-local start offset
    if (q == 0) hoff[(size_t)tile * HROW + NBQ] = (uint32_t)cnt;
    h[q] = lstart;                                    // placement cursor
    __syncthreads();
    // phase 3: place into LDS sorted order
    #pragma unroll
    for (int e = 0; e < 16; ++e) {
        if (a[e] != 0xFFFFFFFFu) {
            uint32_t qq = a[e] >> 14;
            uint32_t u = (vpk[e >> 1] >> ((e & 1) * 16)) & 0xFFFFu;
            srt[atomicAdd(&h[qq], 1u)] = (u << 16) | (a[e] & 16383u);
        }
    }
    __syncthreads();
    // phase 4: fully coalesced linear writeout (uint4)
    uint4* recq = (uint4*)(rec + (size_t)tile * TP);
    const uint4* sr4 = (const uint4*)srt;
    for (int s = threadIdx.x; s < (cnt >> 2); s += 1024) recq[s] = sr4[s];
}

// K2: per-bucket LDS accumulate (swizzled 64 KB). 8-lane group grp handles
// tiles grp and grp+128 (NTILE=245 -> at most 2), runs of ~16 records each.
__global__ void __launch_bounds__(1024, 8) accum_k(const uint32_t* __restrict__ rec,
                                                   const uint32_t* __restrict__ hoff,
                                                   uint16_t* __restrict__ faces,
                                                   float2* __restrict__ pa) {
    __shared__ float g[16384];   // voxel (s = il*32+jl, kl) at gaddr(s,kl)
    int qb = blockIdx.x;
    {
        float4 z = make_float4(0.f, 0.f, 0.f, 0.f);
        #pragma unroll
        for (int c = 0; c < 4; ++c)
            *(float4*)&g[(threadIdx.x + c * 1024) * 4] = z;
    }
    __syncthreads();
    {
        int grp = threadIdx.x >> 3;      // 0..127
        int r8  = threadIdx.x & 7;
        // tile A = grp (always < 245), tile B = grp + 128 (valid if < 245)
        const uint32_t* rowA = hoff + (size_t)grp * HROW;
        uint32_t a0 = rowA[qb], a1 = rowA[qb + 1];
        const uint32_t* rpA = rec + (size_t)grp * TP;
        int tB = grp + 128;
        uint32_t b0 = 0, b1 = 0;
        const uint32_t* rpB = nullptr;
        if (tB < NTILE) {
            const uint32_t* rowB = hoff + (size_t)tB * HROW;
            b0 = rowB[qb]; b1 = rowB[qb + 1];
            rpB = rec + (size_t)tB * TP;
        }
        for (uint32_t r = a0 + r8; r < a1; r += 8) {
            uint32_t e = rpA[r];
            int l = e & 16383;
            atomicAdd(&g[gaddr(l >> 4, l & 15)], __uint_as_float(e & 0xFFFF0000u));
        }
        if (rpB) {
            for (uint32_t r = b0 + r8; r < b1; r += 8) {
                uint32_t e = rpB[r];
                int l = e & 16383;
                atomicAdd(&g[gaddr(l >> 4, l & 15)], __uint_as_float(e & 0xFFFF0000u));
            }
        }
    }
    __syncthreads();
    // stencil: thread t owns line s = t (il = t>>5, jl = t&31)
    float tv = 0.f, mse = 0.f;
    {
        int s = threadIdx.x;
        int jl = s & 31, il = s >> 5;
        bool jin = jl < 31, iin = il < 31;
        float own[16];
        #pragma unroll
        for (int c = 0; c < 4; ++c)
            *(float4*)&own[c * 4] = *(const float4*)&g[s * 16 + goff(s, c)];
        #pragma unroll
        for (int k = 0; k < 15; ++k) {
            float d = own[k + 1] - own[k]; tv += fabsf(d); mse += d * d;
        }
        #pragma unroll
        for (int hh = 0; hh < 2; ++hh) {
            if (jin) {
                float jn[8];
                *(float4*)&jn[0] = *(const float4*)&g[(s + 1) * 16 + goff(s + 1, 2 * hh)];
                *(float4*)&jn[4] = *(const float4*)&g[(s + 1) * 16 + goff(s + 1, 2 * hh + 1)];
                #pragma unroll
                for (int k = 0; k < 8; ++k) {
                    float d = jn[k] - own[8 * hh + k]; tv += fabsf(d); mse += d * d;
                }
            }
            if (iin) {
                float inb[8];
                *(float4*)&inb[0] = *(const float4*)&g[(s + 32) * 16 + goff(s + 32, 2 * hh)];
                *(float4*)&inb[4] = *(const float4*)&g[(s + 32) * 16 + goff(s + 32, 2 * hh + 1)];
                #pragma unroll
                for (int k = 0; k < 8; ++k) {
                    float d = inb[k] - own[8 * hh + k]; tv += fabsf(d); mse += d * d;
                }
            }
        }
    }
    // faces (ushort = top-16 float bits): layout as before
    {
        uint16_t* f = faces + (size_t)qb * 4096;
        int t = threadIdx.x;
        if (t < 512) {
            int hi = t >> 4, lo = t & 15;
            f[t]        = (uint16_t)(__float_as_uint(g[gaddr(hi, lo)]) >> 16);
            f[512 + t]  = (uint16_t)(__float_as_uint(g[gaddr(992 + hi, lo)]) >> 16);
            f[1024 + t] = (uint16_t)(__float_as_uint(g[gaddr(hi * 32, lo)]) >> 16);
            f[1536 + t] = (uint16_t)(__float_as_uint(g[gaddr(hi * 32 + 31, lo)]) >> 16);
        }
        f[2048 + t] = (uint16_t)(__float_as_uint(g[gaddr(t, 0)]) >> 16);
        f[3072 + t] = (uint16_t)(__float_as_uint(g[gaddr(t, 15)]) >> 16);
    }
    block_reduce2<1024>(tv, mse);
    if (threadIdx.x == 0) pa[qb] = make_float2(tv, mse);
}

__device__ __forceinline__ float f16up(uint16_t u) {
    return __uint_as_float(((uint32_t)u) << 16);
}

// K3: cross-sub-block interface diffs from face arrays (batch-major partials)
__global__ void __launch_bounds__(256) boundary_k(const uint16_t* __restrict__ faces,
                                                  float2* __restrict__ pb) {
    int x = blockIdx.x;
    int b = x / NIFACE;
    int r = x - b * NIFACE;
    int qA, qB, fA, fB, elems;
    if (r < 96) {                       // axis i
        int s = r >> 5, u = (r >> 3) & 3, w = r & 7;
        qA = (b << 7) | (s << 5) | (u << 3) | w; qB = qA + 32;
        fA = 512; fB = 0; elems = 512;
    } else if (r < 192) {               // axis j
        int r2 = r - 96;
        int s = r2 >> 5, u = (r2 >> 3) & 3, w = r2 & 7;
        qA = (b << 7) | (u << 5) | (s << 3) | w; qB = qA + 8;
        fA = 1536; fB = 1024; elems = 512;
    } else {                            // axis k
        int r2 = r - 192;
        int s = r2 >> 4, u = (r2 >> 2) & 3, v = r2 & 3;
        qA = (b << 7) | (u << 5) | (v << 3) | s; qB = qA + 1;
        fA = 3072; fB = 2048; elems = 1024;
    }
    const uint16_t* pA = faces + (size_t)qA * 4096 + fA;
    const uint16_t* pB = faces + (size_t)qB * 4096 + fB;
    float tv = 0.f, mse = 0.f;
    for (int e = threadIdx.x; e < elems; e += 256) {
        float d = f16up(pB[e]) - f16up(pA[e]);
        tv += fabsf(d); mse += d * d;
    }
    block_reduce2<256>(tv, mse);
    if (threadIdx.x == 0) pb[x] = make_float2(tv, mse);
}

// K4: final reduction — one block per batch, no atomics
__global__ void __launch_bounds__(256) final_k(const float2* __restrict__ pa,
                                               const float2* __restrict__ pb,
                                               float* __restrict__ out) {
    int b = blockIdx.x;
    float tv = 0.f, mse = 0.f;
    const float2* a = pa + (size_t)b * (NBQ / BATCH);
    for (int i = threadIdx.x; i < NBQ / BATCH; i += 256) { float2 v = a[i]; tv += v.x; mse += v.y; }
    const float2* p = pb + (size_t)b * NIFACE;
    for (int i = threadIdx.x; i < NIFACE; i += 256) { float2 v = p[i]; tv += v.x; mse += v.y; }
    block_reduce2<256>(tv, mse);
    if (threadIdx.x == 0) {
        out[b]     = tv  * (1.f / 2097152.f);   // / X^3
        out[8 + b] = mse * (1.f / 32512.f);     // / (2X^2-2X)
    }
}

extern "C" void kernel_launch(void* const* d_in, const int* in_sizes, int n_in,
                              void* d_out, int out_size, void* d_ws, size_t ws_size,
                              hipStream_t stream) {
    const int*   indices = (const int*)d_in[0];   // (B, M, 3) int32
    const float* values  = (const float*)d_in[1]; // (B, M) float32
    float*       out     = (float*)d_out;         // (2, B) float32

    // workspace (~26 MiB), 256B-aligned sections
    char* wp = (char*)d_ws;
    uint32_t* hoff  = (uint32_t*)wp;                           // NTILE*HROW (1.0 MB)
    wp += (((size_t)NTILE * HROW * 4) + 255) & ~(size_t)255;
    float2*   pa    = (float2*)wp;                             // NBQ        (8 KB)
    wp += (NBQ * 8 + 255) & ~(size_t)255;
    float2*   pb    = (float2*)wp;                             // NBND       (19 KB)
    wp += ((size_t)NBND * 8 + 255) & ~(size_t)255;
    uint32_t* rec   = (uint32_t*)wp;                           // NPTS+pad   (16 MB)
    wp += (((size_t)NTILE * TP * 4) + 255) & ~(size_t)255;
    uint16_t* faces = (uint16_t*)wp;                           // NBQ*4096   (8 MB)

    sort_k    <<<NTILE, 1024, 0, stream>>>(indices, values, hoff, rec);
    accum_k   <<<NBQ,   1024, 0, stream>>>(rec, hoff, faces, pa);
    boundary_k<<<NBND,  256,  0, stream>>>(faces, pb);
    final_k   <<<BATCH, 256,  0, stream>>>(pa, pb, out);
}